// Round 11
// baseline (300.926 us; speedup 1.0000x reference)
//
#include <hip/hip_runtime.h>
#include <hip/hip_fp16.h>

#define N_NODES    100000
#define N_EDGES    3200000
#define IN_DIM     128
#define EMB        32
#define NUM_GRAPHS 256

#define FB         1024      // coarse buckets (782 used: bucket = dst >> 7)
#define PAD        16        // ints per bucket counter -> one 64B line each
#define NODES_PB   128       // nodes per bucket
#define NBUCKETS   782       // ceil(N_NODES / 128)
#define F1_EPB     4000      // edges per fill block
#define F1_BLOCKS  800       // 800 * 4000 == N_EDGES
#define H_EPB      2048      // edges per hist block
#define H_BLOCKS   1563      // ceil(N_EDGES / H_EPB)
#define XW_BLOCKS  1563      // ceil(N_NODES / 64)
#define CAP        5632      // fill2 LDS staging (mean 4092, +24 sigma)

typedef _Float16 half8 __attribute__((ext_vector_type(8)));
typedef float floatx4 __attribute__((ext_vector_type(4)));

// ---------------------------------------------------------------------------
// Coarse histogram of dst>>7. chist_p is line-padded (stride 16 ints): global
// atomic chains serialize PER CACHE LINE (~2.3ns/op, R9/R10 fit), so padding
// makes chain depth = #blocks, not #blocks*16. 1563 blocks for latency hiding.
// ---------------------------------------------------------------------------
__global__ __launch_bounds__(256) void k_hist1(const int* __restrict__ ei,
                                               int* __restrict__ chist_p) {
    __shared__ int h[FB];
    int t = threadIdx.x;
    for (int i = t; i < FB; i += 256) h[i] = 0;
    __syncthreads();
    int e0 = blockIdx.x * H_EPB;
    for (int k = t; k < H_EPB; k += 256) {
        int e = e0 + k;
        if (e < N_EDGES) atomicAdd(&h[ei[N_EDGES + e] >> 7], 1);
    }
    __syncthreads();
    for (int i = t; i < FB; i += 256)
        if (h[i]) atomicAdd(&chist_p[i * PAD], h[i]);
}

// ---------------------------------------------------------------------------
// Aux (2 blocks x 512): block 0 = exclusive scan of padded chist -> cbase
// (compact, read-only) + gcursor_p (line-padded, atomically reserved by
// fill1); block 1 = zero sums + per-graph counts via binary search.
// ---------------------------------------------------------------------------
__global__ __launch_bounds__(512) void k_aux(const int* __restrict__ chist_p,
                                             int* __restrict__ cbase,
                                             int* __restrict__ gcursor_p,
                                             const int* __restrict__ batch,
                                             float* __restrict__ sums,
                                             float* __restrict__ counts) {
    int t = threadIdx.x;
    if (blockIdx.x == 0) {
        __shared__ int ts[512];
        int v0 = chist_p[(2 * t) * PAD], v1 = chist_p[(2 * t + 1) * PAD];
        int tot = v0 + v1;
        ts[t] = tot;
        __syncthreads();
        for (int off = 1; off < 512; off <<= 1) {
            int u = (t >= off) ? ts[t - off] : 0;
            __syncthreads();
            ts[t] += u;
            __syncthreads();
        }
        int base = ts[t] - tot;
        cbase[2 * t] = base;          gcursor_p[(2 * t) * PAD] = base;
        cbase[2 * t + 1] = base + v0; gcursor_p[(2 * t + 1) * PAD] = base + v0;
        if (t == 511) cbase[FB] = ts[511];
    } else {
        for (int i = t; i < NUM_GRAPHS * EMB; i += 512) sums[i] = 0.f;
        if (t < NUM_GRAPHS) {
            int lo = 0, hi = N_NODES;
            while (lo < hi) { int mid = (lo + hi) >> 1; if (batch[mid] < t) lo = mid + 1; else hi = mid; }
            int a = lo;
            lo = 0; hi = N_NODES;
            int g1 = t + 1;
            while (lo < hi) { int mid = (lo + hi) >> 1; if (batch[mid] < g1) lo = mid + 1; else hi = mid; }
            counts[t] = (float)(lo - a);
        }
    }
}

// ---------------------------------------------------------------------------
// Fill1: group edges by bucket (dst>>7). 800 blocks (3.1/CU — latency hidden),
// register-buffered single ei pass, direct global placement. Reservation
// atomics hit line-padded gcursor_p: chain = 800 * 2.3ns ~ 2us.
// rec = (dst&127)<<24 | src
// ---------------------------------------------------------------------------
__global__ __launch_bounds__(512) void k_fill1(const int* __restrict__ ei,
                                               int* __restrict__ gcursor_p,
                                               unsigned int* __restrict__ recs) {
    __shared__ int hist[FB];
    __shared__ int base[FB];
    __shared__ int lcur[FB];
    int t = threadIdx.x;
    for (int i = t; i < FB; i += 512) { hist[i] = 0; lcur[i] = 0; }
    __syncthreads();
    int e0 = blockIdx.x * F1_EPB;
    int s[8], d[8];
#pragma unroll
    for (int k = 0; k < 8; ++k) {
        int idx = k * 512 + t;
        if (idx < F1_EPB) {
            int e = e0 + idx;
            s[k] = ei[e];
            d[k] = ei[N_EDGES + e];
            atomicAdd(&hist[d[k] >> 7], 1);
        } else {
            d[k] = -1;
        }
    }
    __syncthreads();
    for (int i = t; i < FB; i += 512)
        if (hist[i]) base[i] = atomicAdd(&gcursor_p[i * PAD], hist[i]);
    __syncthreads();
#pragma unroll
    for (int k = 0; k < 8; ++k) {
        if (d[k] >= 0) {
            int b = d[k] >> 7;
            int pos = base[b] + atomicAdd(&lcur[b], 1);
            recs[pos] = ((unsigned int)(d[k] & 127) << 24) | (unsigned int)s[k];
        }
    }
}

// ---------------------------------------------------------------------------
// Fill2: one block per 128-node bucket (782 blocks, ~24 KB LDS -> 6/CU).
// LDS histogram of bucket's recs -> deg -> rowstart + dinv + cursors; staged
// counting sort emits edge_src.
// ---------------------------------------------------------------------------
__global__ __launch_bounds__(512) void k_fill2(const unsigned int* __restrict__ recs,
                                               const int* __restrict__ cbase,
                                               int* __restrict__ edge_src,
                                               int* __restrict__ rowstart,
                                               float* __restrict__ dinv) {
    __shared__ unsigned int lbuf[CAP];          // 22 KB
    __shared__ int h2[NODES_PB], cur2[NODES_PB], sc[NODES_PB];
    int t = threadIdx.x, b = blockIdx.x;
    if (t < NODES_PB) h2[t] = 0;
    __syncthreads();
    int seg0 = cbase[b];
    int cnt = cbase[b + 1] - seg0;
    for (int j = t; j < cnt; j += 512) {
        unsigned int r = recs[seg0 + j];
        if (j < CAP) lbuf[j] = r;
        atomicAdd(&h2[r >> 24], 1);
    }
    __syncthreads();
    int v = 0;
    if (t < NODES_PB) { v = h2[t]; sc[t] = v; }
    __syncthreads();
    for (int off = 1; off < NODES_PB; off <<= 1) {
        int u = 0;
        if (t < NODES_PB && t >= off) u = sc[t - off];
        __syncthreads();
        if (t < NODES_PB) sc[t] += u;
        __syncthreads();
    }
    int node0 = b << 7;
    if (t < NODES_PB) {
        int excl = sc[t] - v;
        cur2[t] = excl;
        int node = node0 + t;
        if (node < N_NODES) {
            rowstart[node] = seg0 + excl;
            dinv[node] = rsqrtf((float)v + 1.0f);
        }
    }
    if (b == 0 && t == 0) rowstart[N_NODES] = N_EDGES;
    __syncthreads();
    for (int j = t; j < cnt; j += 512) {
        unsigned int r = (j < CAP) ? lbuf[j] : recs[seg0 + j];
        int p = atomicAdd(&cur2[r >> 24], 1);
        edge_src[seg0 + p] = (int)(r & 0x00FFFFFF);
    }
}

// ---------------------------------------------------------------------------
// xw = (x @ W1) * dinv[row] -> fp16 via MFMA 16x16x32_f16 (one wave = 16
// rows). Runs AFTER fill2 so the dinv scale folds in here. Wh padded to
// stride 33 -> bfrag reads conflict-free.
// ---------------------------------------------------------------------------
__global__ __launch_bounds__(256) void k_xw(const float* __restrict__ x,
                                            const float* __restrict__ W1,
                                            const float* __restrict__ dinv,
                                            __half* __restrict__ xwh) {
    __shared__ _Float16 Wh[IN_DIM * (EMB + 1)];   // 8.25 KB, padded stride 33
    for (int i = threadIdx.x; i < IN_DIM * EMB; i += 256)
        Wh[(i >> 5) * (EMB + 1) + (i & 31)] = (_Float16)W1[i];
    __syncthreads();
    int wave = threadIdx.x >> 6;
    int lane = threadIdx.x & 63;
    int m = lane & 15, quad = lane >> 4;
    int row0 = (blockIdx.x * 4 + wave) * 16;
    if (row0 >= N_NODES) return;
    half8 bfrag[2][4];
#pragma unroll
    for (int nt = 0; nt < 2; ++nt)
#pragma unroll
        for (int ks = 0; ks < 4; ++ks)
#pragma unroll
            for (int j = 0; j < 8; ++j)
                bfrag[nt][ks][j] = Wh[(ks * 32 + quad * 8 + j) * (EMB + 1) + nt * 16 + m];
    const float* xr = x + (size_t)(row0 + m) * IN_DIM + quad * 8;
    floatx4 c0 = {0.f, 0.f, 0.f, 0.f}, c1 = {0.f, 0.f, 0.f, 0.f};
#pragma unroll
    for (int ks = 0; ks < 4; ++ks) {
        float4 a0 = *(const float4*)(xr + ks * 32);
        float4 a1 = *(const float4*)(xr + ks * 32 + 4);
        half8 af;
        af[0] = (_Float16)a0.x; af[1] = (_Float16)a0.y;
        af[2] = (_Float16)a0.z; af[3] = (_Float16)a0.w;
        af[4] = (_Float16)a1.x; af[5] = (_Float16)a1.y;
        af[6] = (_Float16)a1.z; af[7] = (_Float16)a1.w;
        c0 = __builtin_amdgcn_mfma_f32_16x16x32_f16(af, bfrag[0][ks], c0, 0, 0, 0);
        c1 = __builtin_amdgcn_mfma_f32_16x16x32_f16(af, bfrag[1][ks], c1, 0, 0, 0);
    }
#pragma unroll
    for (int r = 0; r < 4; ++r) {
        int ro = row0 + quad * 4 + r;
        float di = dinv[ro];
        xwh[(size_t)ro * EMB + m]      = __float2half(c0[r] * di);
        xwh[(size_t)ro * EMB + 16 + m] = __float2half(c1[r] * di);
    }
}

// ---------------------------------------------------------------------------
// Gather step helper: K parallel gathers (loads issued together, then summed)
// ---------------------------------------------------------------------------
template<int K>
__device__ __forceinline__ void gstep(const int* __restrict__ es,
                                      const __half2* __restrict__ rows,
                                      int cc, int e, float& a0, float& a1) {
    int s[K];
    float2 f[K];
#pragma unroll
    for (int k = 0; k < K; ++k) s[k] = es[e + k];
#pragma unroll
    for (int k = 0; k < K; ++k) f[k] = __half22float2(rows[s[k] * 16 + cc]);
#pragma unroll
    for (int k = 0; k < K; ++k) { a0 += f[k].x; a1 += f[k].y; }
}

// ---------------------------------------------------------------------------
// Fused gather, half2: 16 lanes per node x 2 cols. Main 16-unroll + binary
// tail ladder. Epilogue: self-loop + tanh + sorted-batch pool.
// ---------------------------------------------------------------------------
__global__ __launch_bounds__(256) void k_gather(const __half* __restrict__ xws,
                                                const float* __restrict__ dinv,
                                                const int* __restrict__ rowstart,
                                                const int* __restrict__ edge_src,
                                                const int* __restrict__ batch,
                                                const float* __restrict__ b1,
                                                float* __restrict__ sums) {
    const __half2* rows = (const __half2*)xws;   // row stride = 16 half2
    int grp = threadIdx.x >> 4;          // node slot 0..15
    int cc  = threadIdx.x & 15;          // half2 column
    int i = blockIdx.x * 16 + grp;
    float di = dinv[i];
    int e0 = rowstart[i], e1 = rowstart[i + 1];
    float a0 = 0.f, a1 = 0.f;
    int e = e0;
    for (; e + 16 <= e1; e += 16) gstep<16>(edge_src, rows, cc, e, a0, a1);
    if (e + 8 <= e1) { gstep<8>(edge_src, rows, cc, e, a0, a1); e += 8; }
    if (e + 4 <= e1) { gstep<4>(edge_src, rows, cc, e, a0, a1); e += 4; }
    if (e + 2 <= e1) { gstep<2>(edge_src, rows, cc, e, a0, a1); e += 2; }
    if (e < e1)      { gstep<1>(edge_src, rows, cc, e, a0, a1); }
    float2 fs = __half22float2(rows[i * 16 + cc]);
    float2 bb = *(const float2*)(b1 + 2 * cc);
    float h0 = tanhf((a0 + fs.x) * di + bb.x);
    float h1 = tanhf((a1 + fs.y) * di + bb.y);

    __shared__ float hs[16][EMB];
    __shared__ int gb[16];
    *(float2*)&hs[grp][2 * cc] = make_float2(h0, h1);
    if (cc == 0) gb[grp] = batch[i];
    __syncthreads();
    if (threadIdx.x < 32) {
        int col = threadIdx.x;
        int rr = 0;
        while (rr < 16) {
            int g0 = gb[rr];
            float a = hs[rr][col];
            int r2 = rr + 1;
            while (r2 < 16 && gb[r2] == g0) { a += hs[r2][col]; ++r2; }
            atomicAdd(&sums[g0 * EMB + col], a);
            rr = r2;
        }
    }
}

// ---------------------------------------------------------------------------
// head: out[g] = [sums, means] @ Wout + bout
// ---------------------------------------------------------------------------
__global__ __launch_bounds__(64) void k_out(const float* __restrict__ sums,
                                            const float* __restrict__ counts,
                                            const float* __restrict__ Wout,
                                            const float* __restrict__ bout,
                                            float* __restrict__ out) {
    int g = blockIdx.x * 64 + threadIdx.x;
    if (g >= NUM_GRAPHS) return;
    float inv = 1.0f / fmaxf(counts[g], 1.0f);
    float acc = bout[0];
#pragma unroll
    for (int c = 0; c < EMB; ++c) {
        float s = sums[g * EMB + c];
        acc += s * Wout[c] + s * inv * Wout[EMB + c];
    }
    out[g] = acc;
}

extern "C" void kernel_launch(void* const* d_in, const int* in_sizes, int n_in,
                              void* d_out, int out_size, void* d_ws, size_t ws_size,
                              hipStream_t stream) {
    const float* x     = (const float*)d_in[0];
    const int*   ei    = (const int*)d_in[1];   // [2, E]
    const int*   batch = (const int*)d_in[2];   // [N], sorted
    const float* W1    = (const float*)d_in[3];
    const float* b1    = (const float*)d_in[4];
    const float* Wout  = (const float*)d_in[5];
    const float* bout  = (const float*)d_in[6];
    float* out = (float*)d_out;

    // workspace (~33.4 MB)
    char* ws = (char*)d_ws;
    __half* xwh        = (__half*)ws;       ws += (size_t)N_NODES * EMB * sizeof(__half);  // 6.4 MB
    unsigned int* recs = (unsigned int*)ws; ws += (size_t)N_EDGES * sizeof(int);           // 12.8 MB
    int*   edge_src    = (int*)ws;          ws += (size_t)N_EDGES * sizeof(int);           // 12.8 MB
    int*   rowstart    = (int*)ws;          ws += (size_t)(N_NODES + 4) * sizeof(int);     // 0.4 MB
    float* dinv        = (float*)ws;        ws += (size_t)N_NODES * sizeof(float);         // 0.4 MB
    int*   chist_p     = (int*)ws;          ws += FB * PAD * sizeof(int);                  // 64 KB
    int*   gcursor_p   = (int*)ws;          ws += FB * PAD * sizeof(int);                  // 64 KB
    int*   cbase       = (int*)ws;          ws += (FB + 2) * sizeof(int);
    float* sums        = (float*)ws;        ws += (size_t)NUM_GRAPHS * EMB * sizeof(float);
    float* counts      = (float*)ws;

    hipMemsetAsync(chist_p, 0, FB * PAD * sizeof(int), stream);

    k_hist1 <<<H_BLOCKS, 256, 0, stream>>>(ei, chist_p);
    k_aux   <<<2, 512, 0, stream>>>(chist_p, cbase, gcursor_p, batch, sums, counts);
    k_fill1 <<<F1_BLOCKS, 512, 0, stream>>>(ei, gcursor_p, recs);
    k_fill2 <<<NBUCKETS, 512, 0, stream>>>(recs, cbase, edge_src, rowstart, dinv);
    k_xw    <<<XW_BLOCKS, 256, 0, stream>>>(x, W1, dinv, xwh);
    k_gather<<<N_NODES / 16, 256, 0, stream>>>(xwh, dinv, rowstart, edge_src, batch, b1, sums);
    k_out   <<<(NUM_GRAPHS + 63) / 64, 64, 0, stream>>>(sums, counts, Wout, bout, out);
}

// Round 12
// 233.678 us; speedup vs baseline: 1.2878x; 1.2878x over previous
//
#include <hip/hip_runtime.h>
#include <hip/hip_fp16.h>

#define N_NODES    100000
#define N_EDGES    3200000
#define IN_DIM     128
#define EMB        32
#define NUM_GRAPHS 256

#define FB         1024      // coarse buckets (782 used: bucket = dst >> 7)
#define NODES_PB   128       // nodes per bucket
#define NBUCKETS   782       // ceil(N_NODES / 128)
#define HB         512       // hist/fill blocks; HB * HB_EPB == N_EDGES
#define HB_EPB     6250
#define XW_BLOCKS  1563      // ceil(N_NODES / 64)
#define CAP        5632      // fill2 LDS staging (mean 4092, +24 sigma)

typedef _Float16 half8 __attribute__((ext_vector_type(8)));
typedef float floatx4 __attribute__((ext_vector_type(4)));

// ---------------------------------------------------------------------------
// Hist: per-block LDS histogram of dst>>7 over its private edge slice, then a
// NON-ATOMIC coalesced write of the whole row H[b][0..FB). R9-R11 lesson:
// global-atomic merges into a shared histogram cost 50-67us no matter the
// layout; the matrix + scan formulation has zero global atomics.
// ---------------------------------------------------------------------------
__global__ __launch_bounds__(512) void k_hist(const int* __restrict__ ei,
                                              int* __restrict__ H) {
    __shared__ int h[FB];
    int t = threadIdx.x;
    for (int i = t; i < FB; i += 512) h[i] = 0;
    __syncthreads();
    int e0 = blockIdx.x * HB_EPB;
    int e1 = e0 + HB_EPB;
    for (int e = e0 + t; e < e1; e += 512)
        atomicAdd(&h[ei[N_EDGES + e] >> 7], 1);
    __syncthreads();
    int* row = H + (size_t)blockIdx.x * FB;
    for (int i = t; i < FB; i += 512) row[i] = h[i];
}

// ---------------------------------------------------------------------------
// Column scan: 16 blocks x 64 threads, one column (bucket) per thread.
// In-place exclusive scan down the HB rows; column total -> chist[c].
// 4x unrolled so 4 loads are in flight before the dependent stores.
// ---------------------------------------------------------------------------
__global__ __launch_bounds__(64) void k_colscan(int* __restrict__ H,
                                                int* __restrict__ chist) {
    int c = blockIdx.x * 64 + threadIdx.x;
    int run = 0;
    for (int b = 0; b < HB; b += 4) {
        int i0 = (b + 0) * FB + c, i1 = (b + 1) * FB + c;
        int i2 = (b + 2) * FB + c, i3 = (b + 3) * FB + c;
        int v0 = H[i0], v1 = H[i1], v2 = H[i2], v3 = H[i3];
        H[i0] = run;
        H[i1] = run + v0;
        H[i2] = run + v0 + v1;
        H[i3] = run + v0 + v1 + v2;
        run += v0 + v1 + v2 + v3;
    }
    chist[c] = run;
}

// ---------------------------------------------------------------------------
// Aux (2 blocks x 1024): block 0 = exclusive scan of chist[1024] -> cbase;
// block 1 = zero sums + per-graph counts via binary search on sorted batch.
// ---------------------------------------------------------------------------
__global__ __launch_bounds__(1024) void k_aux(const int* __restrict__ chist,
                                              int* __restrict__ cbase,
                                              const int* __restrict__ batch,
                                              float* __restrict__ sums,
                                              float* __restrict__ counts) {
    int t = threadIdx.x;
    if (blockIdx.x == 0) {
        __shared__ int ts[FB];
        int v = chist[t];
        ts[t] = v;
        __syncthreads();
        for (int off = 1; off < FB; off <<= 1) {
            int u = (t >= off) ? ts[t - off] : 0;
            __syncthreads();
            ts[t] += u;
            __syncthreads();
        }
        cbase[t] = ts[t] - v;
        if (t == FB - 1) cbase[FB] = ts[FB - 1];
    } else {
        for (int i = t; i < NUM_GRAPHS * EMB; i += 1024) sums[i] = 0.f;
        if (t < NUM_GRAPHS) {
            int lo = 0, hi = N_NODES;
            while (lo < hi) { int mid = (lo + hi) >> 1; if (batch[mid] < t) lo = mid + 1; else hi = mid; }
            int a = lo;
            lo = 0; hi = N_NODES;
            int g1 = t + 1;
            while (lo < hi) { int mid = (lo + hi) >> 1; if (batch[mid] < g1) lo = mid + 1; else hi = mid; }
            counts[t] = (float)(lo - a);
        }
    }
}

// ---------------------------------------------------------------------------
// Fill: deterministic placement. lcur[i] = cbase[i] + H[myrow][i] (this
// block's reserved range), then stream the same edge slice as k_hist and
// place via LDS cursor atomics. Zero global atomics.
// rec = (dst&127)<<24 | src
// ---------------------------------------------------------------------------
__global__ __launch_bounds__(512) void k_fill(const int* __restrict__ ei,
                                              const int* __restrict__ H,
                                              const int* __restrict__ cbase,
                                              unsigned int* __restrict__ recs) {
    __shared__ int lcur[FB];
    int t = threadIdx.x;
    const int* row = H + (size_t)blockIdx.x * FB;
    for (int i = t; i < FB; i += 512) lcur[i] = cbase[i] + row[i];
    __syncthreads();
    int e0 = blockIdx.x * HB_EPB;
    int e1 = e0 + HB_EPB;
    for (int e = e0 + t; e < e1; e += 512) {
        int s = ei[e];
        int d = ei[N_EDGES + e];
        int pos = atomicAdd(&lcur[d >> 7], 1);
        recs[pos] = ((unsigned int)(d & 127) << 24) | (unsigned int)s;
    }
}

// ---------------------------------------------------------------------------
// Fill2: one block per 128-node bucket (782 blocks, ~24 KB LDS -> 6/CU).
// LDS histogram of bucket's recs -> deg -> rowstart + dinv + cursors; staged
// counting sort emits edge_src.
// ---------------------------------------------------------------------------
__global__ __launch_bounds__(512) void k_fill2(const unsigned int* __restrict__ recs,
                                               const int* __restrict__ cbase,
                                               int* __restrict__ edge_src,
                                               int* __restrict__ rowstart,
                                               float* __restrict__ dinv) {
    __shared__ unsigned int lbuf[CAP];          // 22 KB
    __shared__ int h2[NODES_PB], cur2[NODES_PB], sc[NODES_PB];
    int t = threadIdx.x, b = blockIdx.x;
    if (t < NODES_PB) h2[t] = 0;
    __syncthreads();
    int seg0 = cbase[b];
    int cnt = cbase[b + 1] - seg0;
    for (int j = t; j < cnt; j += 512) {
        unsigned int r = recs[seg0 + j];
        if (j < CAP) lbuf[j] = r;
        atomicAdd(&h2[r >> 24], 1);
    }
    __syncthreads();
    int v = 0;
    if (t < NODES_PB) { v = h2[t]; sc[t] = v; }
    __syncthreads();
    for (int off = 1; off < NODES_PB; off <<= 1) {
        int u = 0;
        if (t < NODES_PB && t >= off) u = sc[t - off];
        __syncthreads();
        if (t < NODES_PB) sc[t] += u;
        __syncthreads();
    }
    int node0 = b << 7;
    if (t < NODES_PB) {
        int excl = sc[t] - v;
        cur2[t] = excl;
        int node = node0 + t;
        if (node < N_NODES) {
            rowstart[node] = seg0 + excl;
            dinv[node] = rsqrtf((float)v + 1.0f);
        }
    }
    if (b == 0 && t == 0) rowstart[N_NODES] = N_EDGES;
    __syncthreads();
    for (int j = t; j < cnt; j += 512) {
        unsigned int r = (j < CAP) ? lbuf[j] : recs[seg0 + j];
        int p = atomicAdd(&cur2[r >> 24], 1);
        edge_src[seg0 + p] = (int)(r & 0x00FFFFFF);
    }
}

// ---------------------------------------------------------------------------
// xw = (x @ W1) * dinv[row] -> fp16 via MFMA 16x16x32_f16 (one wave = 16
// rows). Runs AFTER fill2 so the dinv scale folds in here. Wh padded to
// stride 33 -> bfrag reads conflict-free.
// ---------------------------------------------------------------------------
__global__ __launch_bounds__(256) void k_xw(const float* __restrict__ x,
                                            const float* __restrict__ W1,
                                            const float* __restrict__ dinv,
                                            __half* __restrict__ xwh) {
    __shared__ _Float16 Wh[IN_DIM * (EMB + 1)];   // 8.25 KB, padded stride 33
    for (int i = threadIdx.x; i < IN_DIM * EMB; i += 256)
        Wh[(i >> 5) * (EMB + 1) + (i & 31)] = (_Float16)W1[i];
    __syncthreads();
    int wave = threadIdx.x >> 6;
    int lane = threadIdx.x & 63;
    int m = lane & 15, quad = lane >> 4;
    int row0 = (blockIdx.x * 4 + wave) * 16;
    if (row0 >= N_NODES) return;
    half8 bfrag[2][4];
#pragma unroll
    for (int nt = 0; nt < 2; ++nt)
#pragma unroll
        for (int ks = 0; ks < 4; ++ks)
#pragma unroll
            for (int j = 0; j < 8; ++j)
                bfrag[nt][ks][j] = Wh[(ks * 32 + quad * 8 + j) * (EMB + 1) + nt * 16 + m];
    const float* xr = x + (size_t)(row0 + m) * IN_DIM + quad * 8;
    floatx4 c0 = {0.f, 0.f, 0.f, 0.f}, c1 = {0.f, 0.f, 0.f, 0.f};
#pragma unroll
    for (int ks = 0; ks < 4; ++ks) {
        float4 a0 = *(const float4*)(xr + ks * 32);
        float4 a1 = *(const float4*)(xr + ks * 32 + 4);
        half8 af;
        af[0] = (_Float16)a0.x; af[1] = (_Float16)a0.y;
        af[2] = (_Float16)a0.z; af[3] = (_Float16)a0.w;
        af[4] = (_Float16)a1.x; af[5] = (_Float16)a1.y;
        af[6] = (_Float16)a1.z; af[7] = (_Float16)a1.w;
        c0 = __builtin_amdgcn_mfma_f32_16x16x32_f16(af, bfrag[0][ks], c0, 0, 0, 0);
        c1 = __builtin_amdgcn_mfma_f32_16x16x32_f16(af, bfrag[1][ks], c1, 0, 0, 0);
    }
#pragma unroll
    for (int r = 0; r < 4; ++r) {
        int ro = row0 + quad * 4 + r;
        float di = dinv[ro];
        xwh[(size_t)ro * EMB + m]      = __float2half(c0[r] * di);
        xwh[(size_t)ro * EMB + 16 + m] = __float2half(c1[r] * di);
    }
}

// ---------------------------------------------------------------------------
// Gather step helper: K parallel gathers (loads issued together, then summed)
// ---------------------------------------------------------------------------
template<int K>
__device__ __forceinline__ void gstep(const int* __restrict__ es,
                                      const __half2* __restrict__ rows,
                                      int cc, int e, float& a0, float& a1) {
    int s[K];
    float2 f[K];
#pragma unroll
    for (int k = 0; k < K; ++k) s[k] = es[e + k];
#pragma unroll
    for (int k = 0; k < K; ++k) f[k] = __half22float2(rows[s[k] * 16 + cc]);
#pragma unroll
    for (int k = 0; k < K; ++k) { a0 += f[k].x; a1 += f[k].y; }
}

// ---------------------------------------------------------------------------
// Fused gather, half2: 16 lanes per node x 2 cols. Main 16-unroll + binary
// tail ladder. Epilogue: self-loop + tanh + sorted-batch pool.
// ---------------------------------------------------------------------------
__global__ __launch_bounds__(256) void k_gather(const __half* __restrict__ xws,
                                                const float* __restrict__ dinv,
                                                const int* __restrict__ rowstart,
                                                const int* __restrict__ edge_src,
                                                const int* __restrict__ batch,
                                                const float* __restrict__ b1,
                                                float* __restrict__ sums) {
    const __half2* rows = (const __half2*)xws;   // row stride = 16 half2
    int grp = threadIdx.x >> 4;          // node slot 0..15
    int cc  = threadIdx.x & 15;          // half2 column
    int i = blockIdx.x * 16 + grp;
    float di = dinv[i];
    int e0 = rowstart[i], e1 = rowstart[i + 1];
    float a0 = 0.f, a1 = 0.f;
    int e = e0;
    for (; e + 16 <= e1; e += 16) gstep<16>(edge_src, rows, cc, e, a0, a1);
    if (e + 8 <= e1) { gstep<8>(edge_src, rows, cc, e, a0, a1); e += 8; }
    if (e + 4 <= e1) { gstep<4>(edge_src, rows, cc, e, a0, a1); e += 4; }
    if (e + 2 <= e1) { gstep<2>(edge_src, rows, cc, e, a0, a1); e += 2; }
    if (e < e1)      { gstep<1>(edge_src, rows, cc, e, a0, a1); }
    float2 fs = __half22float2(rows[i * 16 + cc]);
    float2 bb = *(const float2*)(b1 + 2 * cc);
    float h0 = tanhf((a0 + fs.x) * di + bb.x);
    float h1 = tanhf((a1 + fs.y) * di + bb.y);

    __shared__ float hs[16][EMB];
    __shared__ int gb[16];
    *(float2*)&hs[grp][2 * cc] = make_float2(h0, h1);
    if (cc == 0) gb[grp] = batch[i];
    __syncthreads();
    if (threadIdx.x < 32) {
        int col = threadIdx.x;
        int rr = 0;
        while (rr < 16) {
            int g0 = gb[rr];
            float a = hs[rr][col];
            int r2 = rr + 1;
            while (r2 < 16 && gb[r2] == g0) { a += hs[r2][col]; ++r2; }
            atomicAdd(&sums[g0 * EMB + col], a);
            rr = r2;
        }
    }
}

// ---------------------------------------------------------------------------
// head: out[g] = [sums, means] @ Wout + bout
// ---------------------------------------------------------------------------
__global__ __launch_bounds__(64) void k_out(const float* __restrict__ sums,
                                            const float* __restrict__ counts,
                                            const float* __restrict__ Wout,
                                            const float* __restrict__ bout,
                                            float* __restrict__ out) {
    int g = blockIdx.x * 64 + threadIdx.x;
    if (g >= NUM_GRAPHS) return;
    float inv = 1.0f / fmaxf(counts[g], 1.0f);
    float acc = bout[0];
#pragma unroll
    for (int c = 0; c < EMB; ++c) {
        float s = sums[g * EMB + c];
        acc += s * Wout[c] + s * inv * Wout[EMB + c];
    }
    out[g] = acc;
}

extern "C" void kernel_launch(void* const* d_in, const int* in_sizes, int n_in,
                              void* d_out, int out_size, void* d_ws, size_t ws_size,
                              hipStream_t stream) {
    const float* x     = (const float*)d_in[0];
    const int*   ei    = (const int*)d_in[1];   // [2, E]
    const int*   batch = (const int*)d_in[2];   // [N], sorted
    const float* W1    = (const float*)d_in[3];
    const float* b1    = (const float*)d_in[4];
    const float* Wout  = (const float*)d_in[5];
    const float* bout  = (const float*)d_in[6];
    float* out = (float*)d_out;

    // workspace (~35.3 MB)
    char* ws = (char*)d_ws;
    __half* xwh        = (__half*)ws;       ws += (size_t)N_NODES * EMB * sizeof(__half);  // 6.4 MB
    unsigned int* recs = (unsigned int*)ws; ws += (size_t)N_EDGES * sizeof(int);           // 12.8 MB
    int*   edge_src    = (int*)ws;          ws += (size_t)N_EDGES * sizeof(int);           // 12.8 MB
    int*   H           = (int*)ws;          ws += (size_t)HB * FB * sizeof(int);           // 2.0 MB
    int*   rowstart    = (int*)ws;          ws += (size_t)(N_NODES + 4) * sizeof(int);     // 0.4 MB
    float* dinv        = (float*)ws;        ws += (size_t)N_NODES * sizeof(float);         // 0.4 MB
    int*   chist       = (int*)ws;          ws += FB * sizeof(int);
    int*   cbase       = (int*)ws;          ws += (FB + 2) * sizeof(int);
    float* sums        = (float*)ws;        ws += (size_t)NUM_GRAPHS * EMB * sizeof(float);
    float* counts      = (float*)ws;

    k_hist   <<<HB, 512, 0, stream>>>(ei, H);
    k_colscan<<<FB / 64, 64, 0, stream>>>(H, chist);
    k_aux    <<<2, 1024, 0, stream>>>(chist, cbase, batch, sums, counts);
    k_fill   <<<HB, 512, 0, stream>>>(ei, H, cbase, recs);
    k_fill2  <<<NBUCKETS, 512, 0, stream>>>(recs, cbase, edge_src, rowstart, dinv);
    k_xw     <<<XW_BLOCKS, 256, 0, stream>>>(x, W1, dinv, xwh);
    k_gather <<<N_NODES / 16, 256, 0, stream>>>(xwh, dinv, rowstart, edge_src, batch, b1, sums);
    k_out    <<<(NUM_GRAPHS + 63) / 64, 64, 0, stream>>>(sums, counts, Wout, bout, out);
}